// Round 9
// baseline (144.100 us; speedup 1.0000x reference)
//
#include <hip/hip_runtime.h>

// N=512, D=512 pairwise scorer, all f32.
// left = E@W1[:D]; right = E@W1[D:]+b1; h = left[i]+right[j]; LN(D); GELU; @W2+b2; sigmoid.
// LN stats decompose over RAW (uncentered) rows:
//   var_h = var_l[i] + var_r[j] + 2*(dot_raw(i,j)/D - ml[i]*mr[j])
//   x_k   = ((l_k + r_k) - ml - mr) * rstd * g_k + be_k
// Two kernels. Never materialize [N,N,D].
// FIXED FLOOR: harness re-poison fill of d_ws (~42us @80% HBM) in timed stream.
// Budget r8: 42.4 fill + 42 k_pair + ~30 (k_gemm+gaps) = 117.4.
// K_GEMM FROZEN: unroll 4/8/16, capped/uncapped all gave identical totals
// (r4-r8) -> stop blind-tuning; its ~25us estimate may largely be gaps.
// LAUNCH_BOUNDS LESSON (r1/r2/r6/r7): second arg imposes a hard VGPR cap;
// cap < live set => scratch spill (WRITE_SIZE 40-100MB tripwire).
// SHAPE LESSON (r5 vs r7): 8x8/52-VGPR beats 16x8/128-VGPR reg-cached.
// r9: k_pair packed-f32 (v_pk_fma via ext_vector_type(2)) -- VALU-issue cut.

#define N_ 512
#define D_ 512

typedef float v2f __attribute__((ext_vector_type(2)));

// ---------------- K1: left/right GEMMs (FROZEN, r8 version) ----------------
__global__ __launch_bounds__(512) void k_gemm(const float* __restrict__ E,
                                              const float* __restrict__ W1,
                                              const float* __restrict__ b1,
                                              float* __restrict__ W /* [1024][512] */) {
    __shared__ float et[512 * 20];  // et[k][r]: addr k*20+r. 40KB. Overlaid by red[8][1024].

    const int t = threadIdx.x;
    const int bg = blockIdx.x;
    const int rg = bg >> 4;                 // 0..31 row group
    const int cg = bg & 15;                 // 0..15 col group (64 combined cols)
    const int r0 = rg * 16;
    const int half = cg >> 3;               // 0: left, 1: right(+b1)
    const int cb = (cg & 7) << 6;           // col base within half (0..448)

    for (int x = t; x < 16 * 128; x += 512) {
        const int r = x >> 7, k4 = (x & 127) << 2;
        float4 v = *(const float4*)&E[(r0 + r) * D_ + k4];
        et[(k4 + 0) * 20 + r] = v.x;
        et[(k4 + 1) * 20 + r] = v.y;
        et[(k4 + 2) * 20 + r] = v.z;
        et[(k4 + 3) * 20 + r] = v.w;
    }
    __syncthreads();

    const int lane = t & 63;
    const int ks = t >> 6;                  // 0..7
    const int kb = ks << 6;
    const int c4 = (lane & 15) << 2;        // 0..60
    const int rq = ((lane >> 4) & 3) << 2;  // 0,4,8,12
    const float* __restrict__ wp = W1 + (half << 18) + (kb << 9) + cb + c4;

    float4 a0 = {0.f, 0.f, 0.f, 0.f}, a1 = {0.f, 0.f, 0.f, 0.f};
    float4 a2 = {0.f, 0.f, 0.f, 0.f}, a3 = {0.f, 0.f, 0.f, 0.f};
#pragma unroll 16
    for (int k = 0; k < 64; ++k) {
        float4 wv = *(const float4*)(wp + (k << 9));
        float4 ev = *(const float4*)&et[(kb + k) * 20 + rq];
        a0.x = fmaf(ev.x, wv.x, a0.x); a0.y = fmaf(ev.x, wv.y, a0.y);
        a0.z = fmaf(ev.x, wv.z, a0.z); a0.w = fmaf(ev.x, wv.w, a0.w);
        a1.x = fmaf(ev.y, wv.x, a1.x); a1.y = fmaf(ev.y, wv.y, a1.y);
        a1.z = fmaf(ev.y, wv.z, a1.z); a1.w = fmaf(ev.y, wv.w, a1.w);
        a2.x = fmaf(ev.z, wv.x, a2.x); a2.y = fmaf(ev.z, wv.y, a2.y);
        a2.z = fmaf(ev.z, wv.z, a2.z); a2.w = fmaf(ev.z, wv.w, a2.w);
        a3.x = fmaf(ev.w, wv.x, a3.x); a3.y = fmaf(ev.w, wv.y, a3.y);
        a3.z = fmaf(ev.w, wv.z, a3.z); a3.w = fmaf(ev.w, wv.w, a3.w);
    }

    __syncthreads();                         // all et reads done
    float* red = et;                         // red[ks][1024], 32KB
    const int ob = (ks << 10) + c4;
    *(float4*)&red[ob + ((rq + 0) << 6)] = a0;
    *(float4*)&red[ob + ((rq + 1) << 6)] = a1;
    *(float4*)&red[ob + ((rq + 2) << 6)] = a2;
    *(float4*)&red[ob + ((rq + 3) << 6)] = a3;
    __syncthreads();

    float2 s = {0.f, 0.f};
#pragma unroll
    for (int k2 = 0; k2 < 8; ++k2) {
        float2 p = *(const float2*)&red[(k2 << 10) + (t << 1)];
        s.x += p.x; s.y += p.y;
    }
    const int ro = t >> 5, co = (t << 1) & 63;
    if (half) {
        float2 bb = *(const float2*)&b1[cb + co];
        s.x += bb.x; s.y += bb.y;
    }
    *(float2*)&W[((half << 9) + r0 + ro) * D_ + cb + co] = s;
}

// ---------------- K2: fused stats -> cov -> rstd -> gelu-dot -> sigmoid ----
// r5 winner structure (8x8 tiles, 2080 blocks x 256 thr, 33KB LDS) + r9
// packed-f32 math: float4 quads = 4 consecutive k -> (x,y)/(z,w) pair into
// v2f; rstd/t2n are k-invariant splats. GELU 2-evals: 22 -> 13 issue slots
// (9 pk-VALU + 4 trans). cov dot: 4 fma -> 2 pk_fma.

// gelu_tanh(x) = x * sigmoid(1.5957691*(x + 0.044715 x^3))
// q = log2(exp(-2y)) = x*(A*x^2+B), B = -2*log2e*0.79788456, A = B*0.044715
// x = ((l+r) - mm)*rst*g + be ; packed 2-wide over adjacent k.
#define GELU2(L2, R2, G2, BE2, W2V, RSTV, T2NV, ACC2)                         \
    do {                                                                      \
        v2f s_ = (L2) + (R2);                                                 \
        v2f x_ = __builtin_elementwise_fma(                                   \
            __builtin_elementwise_fma(s_, (RSTV), (T2NV)), (G2), (BE2));      \
        v2f q_ = x_ * __builtin_elementwise_fma(                              \
            (v2f){-0.10294340f, -0.10294340f}, x_ * x_,                       \
            (v2f){-2.30220935f, -2.30220935f});                               \
        v2f e_;                                                               \
        e_.x = __builtin_amdgcn_exp2f(q_.x);                                  \
        e_.y = __builtin_amdgcn_exp2f(q_.y);                                  \
        v2f one_ = (v2f){1.f, 1.f} + e_;                                      \
        v2f r_;                                                               \
        r_.x = __builtin_amdgcn_rcpf(one_.x);                                 \
        r_.y = __builtin_amdgcn_rcpf(one_.y);                                 \
        ACC2 = __builtin_elementwise_fma(x_ * r_, (W2V), ACC2);               \
    } while (0)

#define BFLY(V)                                                               \
    do {                                                                      \
        V += __shfl_xor(V, 1, 64);                                            \
        V += __shfl_xor(V, 2, 64);                                            \
        V += __shfl_xor(V, 4, 64);                                            \
        V += __shfl_xor(V, 8, 64);                                            \
    } while (0)

__global__ __launch_bounds__(256, 4) void k_pair(const float* __restrict__ W,
                                                 const float* __restrict__ gf,
                                                 const float* __restrict__ bef,
                                                 const float* __restrict__ wf,
                                                 const float* __restrict__ b2f,
                                                 float* __restrict__ out) {
    __shared__ float ls[8][516];    // 516 mod 32 = 4 -> reads spread banks
    __shared__ float rs[8][516];
    __shared__ float smean[16];     // rows 0-7: ls, 8-15: rs
    __shared__ float svar[16];

    // decode upper-triangle tile index b -> (I, J), I<=J, 64 tile-rows
    const int b = blockIdx.x;
    int I = (int)((129.0f - sqrtf(16641.0f - 8.0f * (float)b)) * 0.5f);
    if (I < 0) I = 0;
    if (I > 63) I = 63;
#define S_(i) (64 * (i) - ((i) * ((i)-1)) / 2)
    while (S_(I) > b) --I;
    while (S_(I + 1) <= b) ++I;
    const int J = I + (b - S_(I));
#undef S_

    const int t = threadIdx.x;
    const int ks = t & 15;          // k-slice: lane bits 0..3 -> shfl-reducible
    const int pt = t >> 4;          // 0..15 pair-threads
    const int i1 = pt & 7;          // l-row
    const int j4 = (pt >> 3) * 4;   // r-col quad base (0 or 4)
    const int Ibase = I * 8, Jbase = N_ + J * 8;

    // ---- stage raw tiles (coalesced 1KB/row chunks, 4 iters) ----
    for (int x = t; x < 8 * 128; x += 256) {
        int r = x >> 7, c4 = (x & 127) << 2;
        *(float4*)&ls[r][c4] = *(const float4*)&W[(Ibase + r) * D_ + c4];
        *(float4*)&rs[r][c4] = *(const float4*)&W[(Jbase + r) * D_ + c4];
    }
    __syncthreads();

    // ---- per-row mean/var from resident tiles (wave-parallel, 4 rows/wave) --
    {
        const int lane = t & 63, w = t >> 6;
#pragma unroll
        for (int rr = 0; rr < 4; ++rr) {
            const int row = w * 4 + rr;                 // 0..15
            const float* p = (row < 8) ? &ls[row][0] : &rs[row - 8][0];
            float4 a = *(const float4*)&p[lane << 2];
            float4 c = *(const float4*)&p[256 + (lane << 2)];
            float sm = (a.x + a.y) + (a.z + a.w) + (c.x + c.y) + (c.z + c.w);
            float sq = a.x * a.x + a.y * a.y + a.z * a.z + a.w * a.w +
                       c.x * c.x + c.y * c.y + c.z * c.z + c.w * c.w;
#pragma unroll
            for (int off = 32; off > 0; off >>= 1) {
                sm += __shfl_xor(sm, off, 64);
                sq += __shfl_xor(sq, off, 64);
            }
            if (lane == 0) {
                float mu = sm * (1.f / D_);
                smean[row] = mu;
                svar[row] = fmaf(-mu, mu, sq * (1.f / D_));
            }
        }
    }
    __syncthreads();

    // ---- pass A: raw cov-dot, packed (2 pk_fma per quad-pair) ----
    v2f cvv0 = {0.f, 0.f}, cvv1 = {0.f, 0.f}, cvv2 = {0.f, 0.f}, cvv3 = {0.f, 0.f};
    for (int it = 0; it < 8; ++it) {
        const int kq = (it * 16 + ks) * 4;
        float4 la = *(float4*)&ls[i1][kq];
        float4 ra = *(float4*)&rs[j4][kq];
        float4 rb = *(float4*)&rs[j4 + 1][kq];
        float4 rc = *(float4*)&rs[j4 + 2][kq];
        float4 rd = *(float4*)&rs[j4 + 3][kq];
        v2f lxy = {la.x, la.y}, lzw = {la.z, la.w};
        cvv0 = __builtin_elementwise_fma(lxy, (v2f){ra.x, ra.y}, cvv0);
        cvv0 = __builtin_elementwise_fma(lzw, (v2f){ra.z, ra.w}, cvv0);
        cvv1 = __builtin_elementwise_fma(lxy, (v2f){rb.x, rb.y}, cvv1);
        cvv1 = __builtin_elementwise_fma(lzw, (v2f){rb.z, rb.w}, cvv1);
        cvv2 = __builtin_elementwise_fma(lxy, (v2f){rc.x, rc.y}, cvv2);
        cvv2 = __builtin_elementwise_fma(lzw, (v2f){rc.z, rc.w}, cvv2);
        cvv3 = __builtin_elementwise_fma(lxy, (v2f){rd.x, rd.y}, cvv3);
        cvv3 = __builtin_elementwise_fma(lzw, (v2f){rd.z, rd.w}, cvv3);
    }
    float cv0 = cvv0.x + cvv0.y, cv1 = cvv1.x + cvv1.y;
    float cv2 = cvv2.x + cvv2.y, cv3 = cvv3.x + cvv3.y;
    BFLY(cv0); BFLY(cv1); BFLY(cv2); BFLY(cv3);

    // ---- rstd + mean-shift in-register ----
    // varh = var_l + var_r + cv*(2/D) - 2*ml*mr + eps ; t2n = -(ml+mr)*rst
    const float ml0 = smean[i1];
    const float vl0 = svar[i1];
    const float mr0 = smean[8 + j4],     mr1 = smean[8 + j4 + 1];
    const float mr2 = smean[8 + j4 + 2], mr3 = smean[8 + j4 + 3];
    const float vr0 = svar[8 + j4],     vr1 = svar[8 + j4 + 1];
    const float vr2 = svar[8 + j4 + 2], vr3 = svar[8 + j4 + 3];
    const float rst0 = rsqrtf(vl0 + vr0 + cv0 * (2.f / D_) - 2.f * ml0 * mr0 + 1e-5f);
    const float rst1 = rsqrtf(vl0 + vr1 + cv1 * (2.f / D_) - 2.f * ml0 * mr1 + 1e-5f);
    const float rst2 = rsqrtf(vl0 + vr2 + cv2 * (2.f / D_) - 2.f * ml0 * mr2 + 1e-5f);
    const float rst3 = rsqrtf(vl0 + vr3 + cv3 * (2.f / D_) - 2.f * ml0 * mr3 + 1e-5f);
    const v2f rstv0 = {rst0, rst0}, rstv1 = {rst1, rst1};
    const v2f rstv2 = {rst2, rst2}, rstv3 = {rst3, rst3};
    const float t2s0 = -(ml0 + mr0) * rst0, t2s1 = -(ml0 + mr1) * rst1;
    const float t2s2 = -(ml0 + mr2) * rst2, t2s3 = -(ml0 + mr3) * rst3;
    const v2f t2nv0 = {t2s0, t2s0}, t2nv1 = {t2s1, t2s1};
    const v2f t2nv2 = {t2s2, t2s2}, t2nv3 = {t2s3, t2s3};

    // ---- pass B: gelu dot, packed ----
    v2f acv0 = {0.f, 0.f}, acv1 = {0.f, 0.f}, acv2 = {0.f, 0.f}, acv3 = {0.f, 0.f};
    for (int it = 0; it < 8; ++it) {
        const int kq = (it * 16 + ks) * 4;
        float4 g4 = *(const float4*)&gf[kq];
        float4 be4 = *(const float4*)&bef[kq];
        float4 w4 = *(const float4*)&wf[kq];
        float4 la = *(float4*)&ls[i1][kq];
        float4 ra = *(float4*)&rs[j4][kq];
        float4 rb = *(float4*)&rs[j4 + 1][kq];
        float4 rc = *(float4*)&rs[j4 + 2][kq];
        float4 rd = *(float4*)&rs[j4 + 3][kq];
        v2f gxy = {g4.x, g4.y}, gzw = {g4.z, g4.w};
        v2f bexy = {be4.x, be4.y}, bezw = {be4.z, be4.w};
        v2f wxy = {w4.x, w4.y}, wzw = {w4.z, w4.w};
        v2f lxy = {la.x, la.y}, lzw = {la.z, la.w};
        GELU2(lxy, ((v2f){ra.x, ra.y}), gxy, bexy, wxy, rstv0, t2nv0, acv0);
        GELU2(lzw, ((v2f){ra.z, ra.w}), gzw, bezw, wzw, rstv0, t2nv0, acv0);
        GELU2(lxy, ((v2f){rb.x, rb.y}), gxy, bexy, wxy, rstv1, t2nv1, acv1);
        GELU2(lzw, ((v2f){rb.z, rb.w}), gzw, bezw, wzw, rstv1, t2nv1, acv1);
        GELU2(lxy, ((v2f){rc.x, rc.y}), gxy, bexy, wxy, rstv2, t2nv2, acv2);
        GELU2(lzw, ((v2f){rc.z, rc.w}), gzw, bezw, wzw, rstv2, t2nv2, acv2);
        GELU2(lxy, ((v2f){rd.x, rd.y}), gxy, bexy, wxy, rstv3, t2nv3, acv3);
        GELU2(lzw, ((v2f){rd.z, rd.w}), gzw, bezw, wzw, rstv3, t2nv3, acv3);
    }
    float ac0 = acv0.x + acv0.y, ac1 = acv1.x + acv1.y;
    float ac2 = acv2.x + acv2.y, ac3 = acv3.x + acv3.y;
    BFLY(ac0); BFLY(ac1); BFLY(ac2); BFLY(ac3);

    // ---- sigmoid + mirrored store (ks==0 lane of each pair-thread) ----
    if (ks == 0) {
        const float bb = b2f[0];
        const float z0 = __builtin_amdgcn_rcpf(
            1.f + __builtin_amdgcn_exp2f(-1.44269504f * (ac0 + bb)));
        const float z1 = __builtin_amdgcn_rcpf(
            1.f + __builtin_amdgcn_exp2f(-1.44269504f * (ac1 + bb)));
        const float z2 = __builtin_amdgcn_rcpf(
            1.f + __builtin_amdgcn_exp2f(-1.44269504f * (ac2 + bb)));
        const float z3 = __builtin_amdgcn_rcpf(
            1.f + __builtin_amdgcn_exp2f(-1.44269504f * (ac3 + bb)));
        const int gi = Ibase + i1;
        const int gj0 = (Jbase - N_) + j4;
        if (I < J) {
            float4 o0 = {z0, z1, z2, z3};
            *(float4*)&out[gi * N_ + gj0] = o0;
            out[gj0 * N_ + gi] = z0;
            out[(gj0 + 1) * N_ + gi] = z1;
            out[(gj0 + 2) * N_ + gi] = z2;
            out[(gj0 + 3) * N_ + gi] = z3;
        } else {  // diagonal tile: only pairs gi<=gj are valid
            if (gi <= gj0)     { out[gi * N_ + gj0] = z0;       out[gj0 * N_ + gi] = z0; }
            if (gi <= gj0 + 1) { out[gi * N_ + gj0 + 1] = z1;   out[(gj0 + 1) * N_ + gi] = z1; }
            if (gi <= gj0 + 2) { out[gi * N_ + gj0 + 2] = z2;   out[(gj0 + 2) * N_ + gi] = z2; }
            if (gi <= gj0 + 3) { out[gi * N_ + gj0 + 3] = z3;   out[(gj0 + 3) * N_ + gi] = z3; }
        }
    }
}

extern "C" void kernel_launch(void* const* d_in, const int* in_sizes, int n_in,
                              void* d_out, int out_size, void* d_ws, size_t ws_size,
                              hipStream_t stream) {
    const float* E     = (const float*)d_in[0];
    const float* W1    = (const float*)d_in[1];
    const float* b1    = (const float*)d_in[2];
    const float* gamma = (const float*)d_in[3];
    const float* beta  = (const float*)d_in[4];
    const float* w2    = (const float*)d_in[5];
    const float* b2    = (const float*)d_in[6];
    float* out = (float*)d_out;

    float* lcrc = (float*)d_ws;       // [1024][512]: rows 0..511 lc, 512..1023 rc(+b1)

    k_gemm<<<512, 512, 0, stream>>>(E, W1, b1, lcrc);
    k_pair<<<2080, 256, 0, stream>>>(lcrc, gamma, beta, w2, b2, out);
}

// Round 10
// 119.414 us; speedup vs baseline: 1.2067x; 1.2067x over previous
//
#include <hip/hip_runtime.h>

// N=512, D=512 pairwise scorer, all f32.
// left = E@W1[:D]; right = E@W1[D:]+b1; h = left[i]+right[j]; LN(D); GELU; @W2+b2; sigmoid.
// LN stats decompose over RAW (uncentered) rows:
//   var_h = var_l[i] + var_r[j] + 2*(dot_raw(i,j)/D - ml[i]*mr[j])
//   x_k   = ((l_k + r_k) - ml - mr) * rstd * g_k + be_k
// Two kernels. Never materialize [N,N,D].
// FIXED FLOOR: harness re-poison fill of d_ws (~42us @80% HBM) in timed stream.
// K_GEMM FROZEN (r4-r8: unroll/cap variants all null on total).
// VGPR-CAP MODEL (r1/r2/r6/r7/r9, empirical): second __launch_bounds__ arg A
// imposes cap ~= 256/A VGPR ((512,2)->128, (256,3)->84, (512,4)/(256,4)->64).
// cap < live set => scratch spill (WRITE_SIZE 40-140MB tripwire). r5 scalar
// k_pair fit 52<64; r9 packed needs ~80-100 -> spilled. Fix: NO second arg
// (HW still gives 4 waves/SIMD at <=128 VGPR = same 16 waves/CU as LDS cap).
// SHAPE LESSON (r5 vs r7): 8x8/low-VGPR beats 16x8/reg-cached.

#define N_ 512
#define D_ 512

typedef float v2f __attribute__((ext_vector_type(2)));

// ---------------- K1: left/right GEMMs (FROZEN, r8 version) ----------------
__global__ __launch_bounds__(512) void k_gemm(const float* __restrict__ E,
                                              const float* __restrict__ W1,
                                              const float* __restrict__ b1,
                                              float* __restrict__ W /* [1024][512] */) {
    __shared__ float et[512 * 20];  // et[k][r]: addr k*20+r. 40KB. Overlaid by red[8][1024].

    const int t = threadIdx.x;
    const int bg = blockIdx.x;
    const int rg = bg >> 4;                 // 0..31 row group
    const int cg = bg & 15;                 // 0..15 col group (64 combined cols)
    const int r0 = rg * 16;
    const int half = cg >> 3;               // 0: left, 1: right(+b1)
    const int cb = (cg & 7) << 6;           // col base within half (0..448)

    for (int x = t; x < 16 * 128; x += 512) {
        const int r = x >> 7, k4 = (x & 127) << 2;
        float4 v = *(const float4*)&E[(r0 + r) * D_ + k4];
        et[(k4 + 0) * 20 + r] = v.x;
        et[(k4 + 1) * 20 + r] = v.y;
        et[(k4 + 2) * 20 + r] = v.z;
        et[(k4 + 3) * 20 + r] = v.w;
    }
    __syncthreads();

    const int lane = t & 63;
    const int ks = t >> 6;                  // 0..7
    const int kb = ks << 6;
    const int c4 = (lane & 15) << 2;        // 0..60
    const int rq = ((lane >> 4) & 3) << 2;  // 0,4,8,12
    const float* __restrict__ wp = W1 + (half << 18) + (kb << 9) + cb + c4;

    float4 a0 = {0.f, 0.f, 0.f, 0.f}, a1 = {0.f, 0.f, 0.f, 0.f};
    float4 a2 = {0.f, 0.f, 0.f, 0.f}, a3 = {0.f, 0.f, 0.f, 0.f};
#pragma unroll 16
    for (int k = 0; k < 64; ++k) {
        float4 wv = *(const float4*)(wp + (k << 9));
        float4 ev = *(const float4*)&et[(kb + k) * 20 + rq];
        a0.x = fmaf(ev.x, wv.x, a0.x); a0.y = fmaf(ev.x, wv.y, a0.y);
        a0.z = fmaf(ev.x, wv.z, a0.z); a0.w = fmaf(ev.x, wv.w, a0.w);
        a1.x = fmaf(ev.y, wv.x, a1.x); a1.y = fmaf(ev.y, wv.y, a1.y);
        a1.z = fmaf(ev.y, wv.z, a1.z); a1.w = fmaf(ev.y, wv.w, a1.w);
        a2.x = fmaf(ev.z, wv.x, a2.x); a2.y = fmaf(ev.z, wv.y, a2.y);
        a2.z = fmaf(ev.z, wv.z, a2.z); a2.w = fmaf(ev.z, wv.w, a2.w);
        a3.x = fmaf(ev.w, wv.x, a3.x); a3.y = fmaf(ev.w, wv.y, a3.y);
        a3.z = fmaf(ev.w, wv.z, a3.z); a3.w = fmaf(ev.w, wv.w, a3.w);
    }

    __syncthreads();                         // all et reads done
    float* red = et;                         // red[ks][1024], 32KB
    const int ob = (ks << 10) + c4;
    *(float4*)&red[ob + ((rq + 0) << 6)] = a0;
    *(float4*)&red[ob + ((rq + 1) << 6)] = a1;
    *(float4*)&red[ob + ((rq + 2) << 6)] = a2;
    *(float4*)&red[ob + ((rq + 3) << 6)] = a3;
    __syncthreads();

    float2 s = {0.f, 0.f};
#pragma unroll
    for (int k2 = 0; k2 < 8; ++k2) {
        float2 p = *(const float2*)&red[(k2 << 10) + (t << 1)];
        s.x += p.x; s.y += p.y;
    }
    const int ro = t >> 5, co = (t << 1) & 63;
    if (half) {
        float2 bb = *(const float2*)&b1[cb + co];
        s.x += bb.x; s.y += bb.y;
    }
    *(float2*)&W[((half << 9) + r0 + ro) * D_ + cb + co] = s;
}

// ---------------- K2: fused stats -> cov -> rstd -> gelu-dot -> sigmoid ----
// r5 winner structure (8x8 tiles, 2080 blocks x 256 thr, 33KB LDS) + packed
// f32 math (v_pk_fma via ext_vector_type(2)); UNCAPPED launch bounds (the r9
// (256,4)->64-VGPR cap spilled the v2f live set).

// gelu_tanh(x) = x * sigmoid(1.5957691*(x + 0.044715 x^3))
// q = log2(exp(-2y)) = x*(A*x^2+B), B = -2*log2e*0.79788456, A = B*0.044715
// x = ((l+r) - mm)*rst*g + be ; packed 2-wide over adjacent k.
#define GELU2(L2, R2, G2, BE2, W2V, RSTV, T2NV, ACC2)                         \
    do {                                                                      \
        v2f s_ = (L2) + (R2);                                                 \
        v2f x_ = __builtin_elementwise_fma(                                   \
            __builtin_elementwise_fma(s_, (RSTV), (T2NV)), (G2), (BE2));      \
        v2f q_ = x_ * __builtin_elementwise_fma(                              \
            (v2f){-0.10294340f, -0.10294340f}, x_ * x_,                       \
            (v2f){-2.30220935f, -2.30220935f});                               \
        v2f e_;                                                               \
        e_.x = __builtin_amdgcn_exp2f(q_.x);                                  \
        e_.y = __builtin_amdgcn_exp2f(q_.y);                                  \
        v2f one_ = (v2f){1.f, 1.f} + e_;                                      \
        v2f r_;                                                               \
        r_.x = __builtin_amdgcn_rcpf(one_.x);                                 \
        r_.y = __builtin_amdgcn_rcpf(one_.y);                                 \
        ACC2 = __builtin_elementwise_fma(x_ * r_, (W2V), ACC2);               \
    } while (0)

#define BFLY(V)                                                               \
    do {                                                                      \
        V += __shfl_xor(V, 1, 64);                                            \
        V += __shfl_xor(V, 2, 64);                                            \
        V += __shfl_xor(V, 4, 64);                                            \
        V += __shfl_xor(V, 8, 64);                                            \
    } while (0)

__global__ __launch_bounds__(256) void k_pair(const float* __restrict__ W,
                                              const float* __restrict__ gf,
                                              const float* __restrict__ bef,
                                              const float* __restrict__ wf,
                                              const float* __restrict__ b2f,
                                              float* __restrict__ out) {
    __shared__ float ls[8][516];    // 516 mod 32 = 4 -> reads spread banks
    __shared__ float rs[8][516];
    __shared__ float smean[16];     // rows 0-7: ls, 8-15: rs
    __shared__ float svar[16];

    // decode upper-triangle tile index b -> (I, J), I<=J, 64 tile-rows
    const int b = blockIdx.x;
    int I = (int)((129.0f - sqrtf(16641.0f - 8.0f * (float)b)) * 0.5f);
    if (I < 0) I = 0;
    if (I > 63) I = 63;
#define S_(i) (64 * (i) - ((i) * ((i)-1)) / 2)
    while (S_(I) > b) --I;
    while (S_(I + 1) <= b) ++I;
    const int J = I + (b - S_(I));
#undef S_

    const int t = threadIdx.x;
    const int ks = t & 15;          // k-slice: lane bits 0..3 -> shfl-reducible
    const int pt = t >> 4;          // 0..15 pair-threads
    const int i1 = pt & 7;          // l-row
    const int j4 = (pt >> 3) * 4;   // r-col quad base (0 or 4)
    const int Ibase = I * 8, Jbase = N_ + J * 8;

    // ---- stage raw tiles (coalesced 1KB/row chunks, 4 iters) ----
    for (int x = t; x < 8 * 128; x += 256) {
        int r = x >> 7, c4 = (x & 127) << 2;
        *(float4*)&ls[r][c4] = *(const float4*)&W[(Ibase + r) * D_ + c4];
        *(float4*)&rs[r][c4] = *(const float4*)&W[(Jbase + r) * D_ + c4];
    }
    __syncthreads();

    // ---- per-row mean/var from resident tiles (wave-parallel, 4 rows/wave) --
    {
        const int lane = t & 63, w = t >> 6;
#pragma unroll
        for (int rr = 0; rr < 4; ++rr) {
            const int row = w * 4 + rr;                 // 0..15
            const float* p = (row < 8) ? &ls[row][0] : &rs[row - 8][0];
            float4 a = *(const float4*)&p[lane << 2];
            float4 c = *(const float4*)&p[256 + (lane << 2)];
            float sm = (a.x + a.y) + (a.z + a.w) + (c.x + c.y) + (c.z + c.w);
            float sq = a.x * a.x + a.y * a.y + a.z * a.z + a.w * a.w +
                       c.x * c.x + c.y * c.y + c.z * c.z + c.w * c.w;
#pragma unroll
            for (int off = 32; off > 0; off >>= 1) {
                sm += __shfl_xor(sm, off, 64);
                sq += __shfl_xor(sq, off, 64);
            }
            if (lane == 0) {
                float mu = sm * (1.f / D_);
                smean[row] = mu;
                svar[row] = fmaf(-mu, mu, sq * (1.f / D_));
            }
        }
    }
    __syncthreads();

    // ---- pass A: raw cov-dot, packed (2 pk_fma per quad-pair) ----
    v2f cvv0 = {0.f, 0.f}, cvv1 = {0.f, 0.f}, cvv2 = {0.f, 0.f}, cvv3 = {0.f, 0.f};
    for (int it = 0; it < 8; ++it) {
        const int kq = (it * 16 + ks) * 4;
        float4 la = *(float4*)&ls[i1][kq];
        float4 ra = *(float4*)&rs[j4][kq];
        float4 rb = *(float4*)&rs[j4 + 1][kq];
        float4 rc = *(float4*)&rs[j4 + 2][kq];
        float4 rd = *(float4*)&rs[j4 + 3][kq];
        v2f lxy = {la.x, la.y}, lzw = {la.z, la.w};
        cvv0 = __builtin_elementwise_fma(lxy, (v2f){ra.x, ra.y}, cvv0);
        cvv0 = __builtin_elementwise_fma(lzw, (v2f){ra.z, ra.w}, cvv0);
        cvv1 = __builtin_elementwise_fma(lxy, (v2f){rb.x, rb.y}, cvv1);
        cvv1 = __builtin_elementwise_fma(lzw, (v2f){rb.z, rb.w}, cvv1);
        cvv2 = __builtin_elementwise_fma(lxy, (v2f){rc.x, rc.y}, cvv2);
        cvv2 = __builtin_elementwise_fma(lzw, (v2f){rc.z, rc.w}, cvv2);
        cvv3 = __builtin_elementwise_fma(lxy, (v2f){rd.x, rd.y}, cvv3);
        cvv3 = __builtin_elementwise_fma(lzw, (v2f){rd.z, rd.w}, cvv3);
    }
    float cv0 = cvv0.x + cvv0.y, cv1 = cvv1.x + cvv1.y;
    float cv2 = cvv2.x + cvv2.y, cv3 = cvv3.x + cvv3.y;
    BFLY(cv0); BFLY(cv1); BFLY(cv2); BFLY(cv3);

    // ---- rstd + mean-shift in-register ----
    // varh = var_l + var_r + cv*(2/D) - 2*ml*mr + eps ; t2n = -(ml+mr)*rst
    const float ml0 = smean[i1];
    const float vl0 = svar[i1];
    const float mr0 = smean[8 + j4],     mr1 = smean[8 + j4 + 1];
    const float mr2 = smean[8 + j4 + 2], mr3 = smean[8 + j4 + 3];
    const float vr0 = svar[8 + j4],     vr1 = svar[8 + j4 + 1];
    const float vr2 = svar[8 + j4 + 2], vr3 = svar[8 + j4 + 3];
    const float rst0 = rsqrtf(vl0 + vr0 + cv0 * (2.f / D_) - 2.f * ml0 * mr0 + 1e-5f);
    const float rst1 = rsqrtf(vl0 + vr1 + cv1 * (2.f / D_) - 2.f * ml0 * mr1 + 1e-5f);
    const float rst2 = rsqrtf(vl0 + vr2 + cv2 * (2.f / D_) - 2.f * ml0 * mr2 + 1e-5f);
    const float rst3 = rsqrtf(vl0 + vr3 + cv3 * (2.f / D_) - 2.f * ml0 * mr3 + 1e-5f);
    const v2f rstv0 = {rst0, rst0}, rstv1 = {rst1, rst1};
    const v2f rstv2 = {rst2, rst2}, rstv3 = {rst3, rst3};
    const float t2s0 = -(ml0 + mr0) * rst0, t2s1 = -(ml0 + mr1) * rst1;
    const float t2s2 = -(ml0 + mr2) * rst2, t2s3 = -(ml0 + mr3) * rst3;
    const v2f t2nv0 = {t2s0, t2s0}, t2nv1 = {t2s1, t2s1};
    const v2f t2nv2 = {t2s2, t2s2}, t2nv3 = {t2s3, t2s3};

    // ---- pass B: gelu dot, packed ----
    v2f acv0 = {0.f, 0.f}, acv1 = {0.f, 0.f}, acv2 = {0.f, 0.f}, acv3 = {0.f, 0.f};
    for (int it = 0; it < 8; ++it) {
        const int kq = (it * 16 + ks) * 4;
        float4 g4 = *(const float4*)&gf[kq];
        float4 be4 = *(const float4*)&bef[kq];
        float4 w4 = *(const float4*)&wf[kq];
        float4 la = *(float4*)&ls[i1][kq];
        float4 ra = *(float4*)&rs[j4][kq];
        float4 rb = *(float4*)&rs[j4 + 1][kq];
        float4 rc = *(float4*)&rs[j4 + 2][kq];
        float4 rd = *(float4*)&rs[j4 + 3][kq];
        v2f gxy = {g4.x, g4.y}, gzw = {g4.z, g4.w};
        v2f bexy = {be4.x, be4.y}, bezw = {be4.z, be4.w};
        v2f wxy = {w4.x, w4.y}, wzw = {w4.z, w4.w};
        v2f lxy = {la.x, la.y}, lzw = {la.z, la.w};
        GELU2(lxy, ((v2f){ra.x, ra.y}), gxy, bexy, wxy, rstv0, t2nv0, acv0);
        GELU2(lzw, ((v2f){ra.z, ra.w}), gzw, bezw, wzw, rstv0, t2nv0, acv0);
        GELU2(lxy, ((v2f){rb.x, rb.y}), gxy, bexy, wxy, rstv1, t2nv1, acv1);
        GELU2(lzw, ((v2f){rb.z, rb.w}), gzw, bezw, wzw, rstv1, t2nv1, acv1);
        GELU2(lxy, ((v2f){rc.x, rc.y}), gxy, bexy, wxy, rstv2, t2nv2, acv2);
        GELU2(lzw, ((v2f){rc.z, rc.w}), gzw, bezw, wzw, rstv2, t2nv2, acv2);
        GELU2(lxy, ((v2f){rd.x, rd.y}), gxy, bexy, wxy, rstv3, t2nv3, acv3);
        GELU2(lzw, ((v2f){rd.z, rd.w}), gzw, bezw, wzw, rstv3, t2nv3, acv3);
    }
    float ac0 = acv0.x + acv0.y, ac1 = acv1.x + acv1.y;
    float ac2 = acv2.x + acv2.y, ac3 = acv3.x + acv3.y;
    BFLY(ac0); BFLY(ac1); BFLY(ac2); BFLY(ac3);

    // ---- sigmoid + mirrored store (ks==0 lane of each pair-thread) ----
    if (ks == 0) {
        const float bb = b2f[0];
        const float z0 = __builtin_amdgcn_rcpf(
            1.f + __builtin_amdgcn_exp2f(-1.44269504f * (ac0 + bb)));
        const float z1 = __builtin_amdgcn_rcpf(
            1.f + __builtin_amdgcn_exp2f(-1.44269504f * (ac1 + bb)));
        const float z2 = __builtin_amdgcn_rcpf(
            1.f + __builtin_amdgcn_exp2f(-1.44269504f * (ac2 + bb)));
        const float z3 = __builtin_amdgcn_rcpf(
            1.f + __builtin_amdgcn_exp2f(-1.44269504f * (ac3 + bb)));
        const int gi = Ibase + i1;
        const int gj0 = (Jbase - N_) + j4;
        if (I < J) {
            float4 o0 = {z0, z1, z2, z3};
            *(float4*)&out[gi * N_ + gj0] = o0;
            out[gj0 * N_ + gi] = z0;
            out[(gj0 + 1) * N_ + gi] = z1;
            out[(gj0 + 2) * N_ + gi] = z2;
            out[(gj0 + 3) * N_ + gi] = z3;
        } else {  // diagonal tile: only pairs gi<=gj are valid
            if (gi <= gj0)     { out[gi * N_ + gj0] = z0;       out[gj0 * N_ + gi] = z0; }
            if (gi <= gj0 + 1) { out[gi * N_ + gj0 + 1] = z1;   out[(gj0 + 1) * N_ + gi] = z1; }
            if (gi <= gj0 + 2) { out[gi * N_ + gj0 + 2] = z2;   out[(gj0 + 2) * N_ + gi] = z2; }
            if (gi <= gj0 + 3) { out[gi * N_ + gj0 + 3] = z3;   out[(gj0 + 3) * N_ + gi] = z3; }
        }
    }
}

extern "C" void kernel_launch(void* const* d_in, const int* in_sizes, int n_in,
                              void* d_out, int out_size, void* d_ws, size_t ws_size,
                              hipStream_t stream) {
    const float* E     = (const float*)d_in[0];
    const float* W1    = (const float*)d_in[1];
    const float* b1    = (const float*)d_in[2];
    const float* gamma = (const float*)d_in[3];
    const float* beta  = (const float*)d_in[4];
    const float* w2    = (const float*)d_in[5];
    const float* b2    = (const float*)d_in[6];
    float* out = (float*)d_out;

    float* lcrc = (float*)d_ws;       // [1024][512]: rows 0..511 lc, 512..1023 rc(+b1)

    k_gemm<<<512, 512, 0, stream>>>(E, W1, b1, lcrc);
    k_pair<<<2080, 256, 0, stream>>>(lcrc, gamma, beta, w2, b2, out);
}